// Round 2
// baseline (472.990 us; speedup 1.0000x reference)
//
#include <hip/hip_runtime.h>

// SegmentedSmoothing: 5x5 clipped-window average where each pixel averages
// only same-class neighbors. Class = boundary band (within BW=10 of any edge)
// vs interior. Input/out: fp32 (4,16,720,1440).
//
// fast_kernel: pure region i in [12,708), j in [12,1428) -> plain 25-sum/25.
//   20 rows/thread, outer loop unroll 1 (4 iters) x inner 5-row static ring
//   (mod-5 phase closes) + 1-row raw-load prefetch to hide VMEM latency
//   without blowing VGPRs (the R1 version full-unrolled 24 rows x 3 loads).
// edge_kernel: masked general path over the thin complex band (4.9% pixels).

#define HH 720
#define WW 1440
#define PLANE (HH * WW)
#define NPLANES 64

#define NG 354       // j0 = 12 + 4*g, g in [0,354): covers j 12..1427
#define CHUNK 20
#define NCHUNK 35    // rows 12..711 covered; stores guarded to r < 708

struct Raw { float2 l; float4 m; float2 r; };

__device__ __forceinline__ Raw load_row(const float* __restrict__ p) {
    Raw o;
    o.l = *(const float2*)(p - 2);  // 8B aligned
    o.m = *(const float4*)(p);      // 16B aligned
    o.r = *(const float2*)(p + 4);  // 16B aligned
    return o;
}

__device__ __forceinline__ float4 combine(const Raw& w) {
    float4 h;
    h.x = w.l.x + w.l.y + w.m.x + w.m.y + w.m.z;
    h.y = h.x - w.l.x + w.m.w;
    h.z = h.y - w.l.y + w.r.x;
    h.w = h.z - w.m.x + w.r.y;
    return h;
}

__device__ __forceinline__ void emit(const float4& a, const float4& b,
                                     const float4& c, const float4& d,
                                     const float4& e, float* __restrict__ q,
                                     int r) {
    if (r < 708) {
        const float s = 1.0f / 25.0f;
        float4 v;
        v.x = (((a.x + b.x) + (c.x + d.x)) + e.x) * s;
        v.y = (((a.y + b.y) + (c.y + d.y)) + e.y) * s;
        v.z = (((a.z + b.z) + (c.z + d.z)) + e.z) * s;
        v.w = (((a.w + b.w) + (c.w + d.w)) + e.w) * s;
        *(float4*)q = v;
    }
}

__global__ __launch_bounds__(256) void fast_kernel(const float* __restrict__ x,
                                                   float* __restrict__ out) {
    const int id = blockIdx.x * 256 + threadIdx.x;
    if (id >= NG * NCHUNK) return;
    const int chunk = id / NG;
    const int g     = id - chunk * NG;
    const int j0    = 12 + 4 * g;
    const int row0  = 12 + chunk * CHUNK;

    const float* __restrict__ xp = x + (size_t)blockIdx.y * PLANE;
    float* __restrict__ op       = out + (size_t)blockIdx.y * PLANE;

    const float* p = xp + (row0 - 2) * WW + j0;
    float4 h0 = combine(load_row(p)); p += WW;
    float4 h1 = combine(load_row(p)); p += WW;
    float4 h2 = combine(load_row(p)); p += WW;
    float4 h3 = combine(load_row(p)); p += WW;
    float4 h4;
    Raw pre = load_row(p); p += WW;   // prefetch row row0+2

    float* q = op + row0 * WW + j0;
    int r = row0;

#pragma unroll 1
    for (int tb = 0; tb < 4; ++tb) {
        h4 = combine(pre); pre = load_row(p); p += WW;
        emit(h0, h1, h2, h3, h4, q, r); q += WW; ++r;
        h0 = combine(pre); pre = load_row(p); p += WW;
        emit(h1, h2, h3, h4, h0, q, r); q += WW; ++r;
        h1 = combine(pre); pre = load_row(p); p += WW;
        emit(h2, h3, h4, h0, h1, q, r); q += WW; ++r;
        h2 = combine(pre); pre = load_row(p); p += WW;
        emit(h3, h4, h0, h1, h2, q, r); q += WW; ++r;
        h3 = combine(pre); pre = load_row(p); p += WW;
        emit(h4, h0, h1, h2, h3, q, r); q += WW; ++r;
    }
    // last prefetch reads row row0+22 <= 714 < 720: always in bounds
}

// ---------------- edge kernel: complex band ----------------
// rows {0..11, 708..719} full width (24*1440=34560) plus rows 12..707 with
// j in {0..11, 1428..1439} (696*24=16704). Total 51264 per plane.

#define NEDGE 51264

__global__ __launch_bounds__(256) void edge_kernel(const float* __restrict__ x,
                                                   float* __restrict__ out) {
    const int p = blockIdx.x * 256 + threadIdx.x;
    if (p >= NEDGE) return;
    int i, j;
    if (p < 34560) {
        i = p / 1440;
        j = p - i * 1440;
        if (i >= 12) i += 696;
    } else {
        const int q  = p - 34560;
        const int qi = q / 24;
        const int rr = q - qi * 24;
        i = 12 + qi;
        j = (rr < 12) ? rr : rr + 1416;
    }

    const float* __restrict__ xp = x + (size_t)blockIdx.y * PLANE;
    const bool cb = (i < 10) | (i >= 710) | (j < 10) | (j >= 1430);

    float s = 0.0f, cnt = 0.0f;
#pragma unroll
    for (int di = -2; di <= 2; ++di) {
#pragma unroll
        for (int dj = -2; dj <= 2; ++dj) {
            const int ni = i + di, nj = j + dj;
            const bool inb = ((unsigned)ni < (unsigned)HH) & ((unsigned)nj < (unsigned)WW);
            const bool nb  = (ni < 10) | (ni >= 710) | (nj < 10) | (nj >= 1430);
            const int ci = min(max(ni, 0), HH - 1);
            const int cj = min(max(nj, 0), WW - 1);
            const float v = xp[ci * WW + cj];
            const float w = (inb && (nb == cb)) ? 1.0f : 0.0f;
            s += w * v;
            cnt += w;
        }
    }
    out[(size_t)blockIdx.y * PLANE + i * WW + j] = s / cnt;
}

extern "C" void kernel_launch(void* const* d_in, const int* in_sizes, int n_in,
                              void* d_out, int out_size, void* d_ws, size_t ws_size,
                              hipStream_t stream) {
    const float* x = (const float*)d_in[0];
    float* out = (float*)d_out;

    dim3 gf((NG * NCHUNK + 255) / 256, NPLANES);
    hipLaunchKernelGGL(fast_kernel, gf, dim3(256), 0, stream, x, out);

    dim3 ge((NEDGE + 255) / 256, NPLANES);
    hipLaunchKernelGGL(edge_kernel, ge, dim3(256), 0, stream, x, out);
}